// Round 1
// baseline (494.495 us; speedup 1.0000x reference)
//
#include <hip/hip_runtime.h>

// Fused SFAM: LayerNorm + 1x1 Q/V projections + bidirectional W-attention + residual.
// One generic "direction" kernel: dir=0 computes out_l (queries=l, keys/V=r),
// dir=1 computes out_r (queries=r, keys/V=l). Grid = 720 rows * 2 dirs.
// Per workgroup: one (b,h) row. 512 threads = 8 waves. LDS ~139 KB -> 1 WG/CU.

#define HWs  57600      // H*W
#define CHWs 3686400    // C*H*W
#define TOTs 14745600   // B*C*H*W
#define RST  72         // row stride (ushort) for pixel-major [320][72] arrays (pad: 2-way-free banks, 16B aligned)
#define VST  328        // row stride (ushort) for channel-major V [64][328]

typedef short bf16x8 __attribute__((ext_vector_type(8)));
typedef float f32x4  __attribute__((ext_vector_type(4)));

union FragU { uint4 q; unsigned short u[8]; bf16x8 v; };

__device__ __forceinline__ unsigned short f2bf(float f) {
  unsigned u = __float_as_uint(f);
  u += 0x7fffu + ((u >> 16) & 1u);     // RNE
  return (unsigned short)(u >> 16);
}
__device__ __forceinline__ float bf2f(unsigned short s) {
  return __uint_as_float(((unsigned)s) << 16);
}

__global__ __launch_bounds__(512, 1) void sfam_kernel(
    const float* __restrict__ x_l, const float* __restrict__ x_r,
    const float* __restrict__ ln_l_w, const float* __restrict__ ln_l_b,
    const float* __restrict__ ln_r_w, const float* __restrict__ ln_r_b,
    const float* __restrict__ wq_l, const float* __restrict__ bq_l,
    const float* __restrict__ wq_r, const float* __restrict__ bq_r,
    const float* __restrict__ wv_l, const float* __restrict__ bv_l,
    const float* __restrict__ wv_r, const float* __restrict__ bv_r,
    const float* __restrict__ beta, const float* __restrict__ gamma,
    float* __restrict__ out)
{
  // LDS: 46080 + 46080 + 41984 + 5120 + 2560 + 512 = 142336 B
  __shared__ __align__(16) unsigned short Rs[320*RST];   // x staging / Qq / P / O
  __shared__ __align__(16) unsigned short QKs[320*RST];  // Q_key, pixel-major [v][o]
  __shared__ __align__(16) unsigned short VCs[64*VST];   // V, channel-major [o][v]
  __shared__ float PS0[320], PS1[320], PQ0[320], PQ1[320];
  __shared__ float MUs[320], RSs[320];
  __shared__ float BQE[64], BKE[64];

  const int bi  = blockIdx.x;
  const int dir = (bi >= 720) ? 1 : 0;
  const int bh  = bi - dir*720;
  const int b   = bh / 180, h = bh - b*180;
  const int base = b*CHWs + h*320;          // + c*HWs + w

  const float* xq   = dir ? x_r   : x_l;
  const float* lnqb = dir ? ln_r_b : ln_l_b;
  const float* lnqw = dir ? ln_r_w : ln_l_w;
  const float* xk   = dir ? x_l   : x_r;
  const float* lnkw = dir ? ln_l_w : ln_r_w;
  const float* lnkb = dir ? ln_l_b : ln_r_b;
  const float* wqq  = dir ? wq_r  : wq_l;
  const float* bqq  = dir ? bq_r  : bq_l;
  const float* wqk  = dir ? wq_l  : wq_r;
  const float* bqk  = dir ? bq_l  : bq_r;
  const float* wv   = dir ? wv_l  : wv_r;   // V always from the KEY side
  const float* bv   = dir ? bv_l  : bv_r;
  const float* scl  = dir ? gamma : beta;
  float* op = out + (dir ? TOTs : 0);

  const int t    = threadIdx.x;
  const int wave = t >> 6, lane = t & 63;
  const int p    = lane & 15, g = lane >> 4;
  // 20 w-tiles of 16 over 8 waves: waves 0..3 take 3 tiles, waves 4..7 take 2.
  const int nwt  = (wave < 4) ? 3 : 2;
  const int w0   = (wave < 4) ? wave*48 : 192 + (wave-4)*32;

  // ---------- P0: effective Q biases (LN bias folded through W) ----------
  if (t < 64) {
    float s = bqq[t];
    for (int c = 0; c < 64; ++c) s += wqq[t*64+c] * lnqb[c];
    BQE[t] = s;
  } else if (t < 128) {
    const int o = t - 64;
    float s = bqk[o];
    for (int c = 0; c < 64; ++c) s += wqk[o*64+c] * lnkb[c];
    BKE[o] = s;
  }

  // ---------- staging: x -> Rs (bf16, pixel-major) + LN stats ----------
  auto stage = [&](const float* xp) {
    for (int idx = t; idx < 640; idx += 512) {
      const int w   = (idx < 320) ? idx : idx - 320;
      const int chf = (idx < 320) ? 0 : 1;
      const int cb  = chf * 32;
      float s = 0.f, qs = 0.f;
      #pragma unroll 8
      for (int c = 0; c < 32; ++c) {
        float v = xp[base + (cb + c)*HWs + w];
        s += v; qs += v*v;
        Rs[w*RST + cb + c] = f2bf(v);
      }
      if (chf == 0) { PS0[w] = s; PQ0[w] = qs; }
      else          { PS1[w] = s; PQ1[w] = qs; }
    }
    __syncthreads();
    if (t < 320) {
      float m  = (PS0[t] + PS1[t]) * (1.f/64.f);
      float va = (PQ0[t] + PQ1[t]) * (1.f/64.f) - m*m;
      MUs[t] = m;
      RSs[t] = rsqrtf(va + 1e-6f);
    }
    __syncthreads();
  };

  // ---------- Q projection: dst[w][o] = scale*( (W*lnw) @ LN(x) + be ) ----------
  auto projQ = [&](const float* wq, const float* lnw, const float* be,
                   unsigned short* dst, float scale) {
    bf16x8 af[3][2];
    #pragma unroll
    for (int wt = 0; wt < 3; ++wt) if (wt < nwt) {
      #pragma unroll
      for (int kf = 0; kf < 2; ++kf) {
        const int w  = w0 + wt*16 + p;
        const int cb = kf*32 + g*8;
        FragU f; f.q = *(const uint4*)&Rs[w*RST + cb];
        const float mu = MUs[w], rs = RSs[w];
        FragU r;
        #pragma unroll
        for (int j = 0; j < 8; ++j) r.u[j] = f2bf((bf2f(f.u[j]) - mu) * rs);
        af[wt][kf] = r.v;
      }
    }
    bf16x8 bfg[4][2];
    #pragma unroll
    for (int ot = 0; ot < 4; ++ot)
      #pragma unroll
      for (int kf = 0; kf < 2; ++kf) {
        const int o  = ot*16 + p;
        const int cb = kf*32 + g*8;
        FragU r;
        #pragma unroll
        for (int j = 0; j < 8; ++j) r.u[j] = f2bf(wq[o*64 + cb + j] * lnw[cb + j]);
        bfg[ot][kf] = r.v;
      }
    f32x4 acc[3][4];
    #pragma unroll
    for (int wt = 0; wt < 3; ++wt)
      #pragma unroll
      for (int ot = 0; ot < 4; ++ot) acc[wt][ot] = (f32x4){0.f,0.f,0.f,0.f};
    #pragma unroll
    for (int wt = 0; wt < 3; ++wt) if (wt < nwt)
      #pragma unroll
      for (int ot = 0; ot < 4; ++ot)
        #pragma unroll
        for (int kf = 0; kf < 2; ++kf)
          acc[wt][ot] = __builtin_amdgcn_mfma_f32_16x16x32_bf16(af[wt][kf], bfg[ot][kf], acc[wt][ot], 0, 0, 0);
    #pragma unroll
    for (int wt = 0; wt < 3; ++wt) if (wt < nwt)
      #pragma unroll
      for (int ot = 0; ot < 4; ++ot)
        #pragma unroll
        for (int r = 0; r < 4; ++r) {
          const int w = w0 + wt*16 + g*4 + r;
          const int o = ot*16 + p;
          dst[w*RST + o] = f2bf((acc[wt][ot][r] + be[o]) * scale);
        }
  };

  // ---------- V projection: VCs[o][w] = Wv @ x_raw + bv ----------
  auto projV = [&]() {
    bf16x8 af[4][2];                       // A = Wv  (m=o, k=c)
    #pragma unroll
    for (int mt = 0; mt < 4; ++mt)
      #pragma unroll
      for (int kf = 0; kf < 2; ++kf) {
        const int o  = mt*16 + p;
        const int cb = kf*32 + g*8;
        FragU r;
        #pragma unroll
        for (int j = 0; j < 8; ++j) r.u[j] = f2bf(wv[o*64 + cb + j]);
        af[mt][kf] = r.v;
      }
    bf16x8 bfg[3][2];                      // B = x_raw from Rs (k=c, n=w)
    #pragma unroll
    for (int nt = 0; nt < 3; ++nt) if (nt < nwt)
      #pragma unroll
      for (int kf = 0; kf < 2; ++kf) {
        const int w  = w0 + nt*16 + p;
        const int cb = kf*32 + g*8;
        FragU f; f.q = *(const uint4*)&Rs[w*RST + cb];
        bfg[nt][kf] = f.v;
      }
    f32x4 acc[4][3];
    #pragma unroll
    for (int mt = 0; mt < 4; ++mt)
      #pragma unroll
      for (int nt = 0; nt < 3; ++nt) acc[mt][nt] = (f32x4){0.f,0.f,0.f,0.f};
    #pragma unroll
    for (int mt = 0; mt < 4; ++mt)
      #pragma unroll
      for (int nt = 0; nt < 3; ++nt) if (nt < nwt)
        #pragma unroll
        for (int kf = 0; kf < 2; ++kf)
          acc[mt][nt] = __builtin_amdgcn_mfma_f32_16x16x32_bf16(af[mt][kf], bfg[nt][kf], acc[mt][nt], 0, 0, 0);
    #pragma unroll
    for (int mt = 0; mt < 4; ++mt)
      #pragma unroll
      for (int nt = 0; nt < 3; ++nt) if (nt < nwt)
        #pragma unroll
        for (int r = 0; r < 4; ++r) {
          const int o = mt*16 + g*4 + r;
          const int w = w0 + nt*16 + p;
          VCs[o*VST + w] = f2bf(acc[mt][nt][r] + bv[o]);
        }
  };

  // ---------- pipeline ----------
  stage(xq);                                  // Rs = xq, stats
  projQ(wqq, lnqw, BQE, Rs, 0.125f);          // Rs rows (wave-private) overwritten with scaled Qq
  bf16x8 aq[3][2];                            // reload Qq as attention A-frags (A[m=w][k=o])
  #pragma unroll
  for (int wt = 0; wt < 3; ++wt) if (wt < nwt)
    #pragma unroll
    for (int kf = 0; kf < 2; ++kf) {
      const int w  = w0 + wt*16 + p;
      const int ob = kf*32 + g*8;
      FragU f; f.q = *(const uint4*)&Rs[w*RST + ob];
      aq[wt][kf] = f.v;
    }
  __syncthreads();                            // everyone done with Rs before restage
  stage(xk);                                  // Rs = xk, stats
  projQ(wqk, lnkw, BKE, QKs, 1.0f);           // QKs[v][o]
  projV();                                    // VCs[o][v]
  __syncthreads();                            // QKs/VCs visible to all waves

  // ---------- attention: 5 chunks of 64 keys, online softmax ----------
  f32x4 oacc[3][4];
  float mst[3][4], lst[3][4], asc[3][4];
  #pragma unroll
  for (int wt = 0; wt < 3; ++wt) {
    #pragma unroll
    for (int ot = 0; ot < 4; ++ot) oacc[wt][ot] = (f32x4){0.f,0.f,0.f,0.f};
    #pragma unroll
    for (int r = 0; r < 4; ++r) { mst[wt][r] = -3.0e38f; lst[wt][r] = 0.f; }
  }

  for (int ch = 0; ch < 5; ++ch) {
    const int v0 = ch*64;
    bf16x8 bk[4][2];
    #pragma unroll
    for (int vt = 0; vt < 4; ++vt)
      #pragma unroll
      for (int kf = 0; kf < 2; ++kf) {
        const int v  = v0 + vt*16 + p;
        const int ob = kf*32 + g*8;
        FragU f; f.q = *(const uint4*)&QKs[v*RST + ob];
        bk[vt][kf] = f.v;
      }
    f32x4 sacc[3][4];
    #pragma unroll
    for (int wt = 0; wt < 3; ++wt)
      #pragma unroll
      for (int vt = 0; vt < 4; ++vt) sacc[wt][vt] = (f32x4){0.f,0.f,0.f,0.f};
    #pragma unroll
    for (int wt = 0; wt < 3; ++wt) if (wt < nwt)
      #pragma unroll
      for (int vt = 0; vt < 4; ++vt)
        #pragma unroll
        for (int kf = 0; kf < 2; ++kf)
          sacc[wt][vt] = __builtin_amdgcn_mfma_f32_16x16x32_bf16(aq[wt][kf], bk[vt][kf], sacc[wt][vt], 0, 0, 0);

    // online softmax (rows live across lanes sharing g; reduce over p via shfl_xor)
    #pragma unroll
    for (int wt = 0; wt < 3; ++wt) if (wt < nwt)
      #pragma unroll
      for (int r = 0; r < 4; ++r) {
        float cm = fmaxf(fmaxf(sacc[wt][0][r], sacc[wt][1][r]),
                         fmaxf(sacc[wt][2][r], sacc[wt][3][r]));
        cm = fmaxf(cm, __shfl_xor(cm, 1));
        cm = fmaxf(cm, __shfl_xor(cm, 2));
        cm = fmaxf(cm, __shfl_xor(cm, 4));
        cm = fmaxf(cm, __shfl_xor(cm, 8));
        const float mn = fmaxf(mst[wt][r], cm);
        const float al = __expf(mst[wt][r] - mn);
        mst[wt][r] = mn;
        float rsum = 0.f;
        #pragma unroll
        for (int vt = 0; vt < 4; ++vt) {
          float pv = __expf(sacc[wt][vt][r] - mn);
          sacc[wt][vt][r] = pv;
          rsum += pv;
        }
        rsum += __shfl_xor(rsum, 1);
        rsum += __shfl_xor(rsum, 2);
        rsum += __shfl_xor(rsum, 4);
        rsum += __shfl_xor(rsum, 8);
        lst[wt][r] = lst[wt][r]*al + rsum;
        asc[wt][r] = al;
      }
    #pragma unroll
    for (int wt = 0; wt < 3; ++wt) if (wt < nwt)
      #pragma unroll
      for (int ot = 0; ot < 4; ++ot)
        #pragma unroll
        for (int r = 0; r < 4; ++r) oacc[wt][ot][r] *= asc[wt][r];

    // P -> LDS (wave-private rows of Rs), then PV MFMAs
    #pragma unroll
    for (int wt = 0; wt < 3; ++wt) if (wt < nwt)
      #pragma unroll
      for (int vt = 0; vt < 4; ++vt)
        #pragma unroll
        for (int r = 0; r < 4; ++r) {
          const int w = w0 + wt*16 + g*4 + r;
          Rs[w*RST + vt*16 + p] = f2bf(sacc[wt][vt][r]);
        }
    bf16x8 ap[3][2];
    #pragma unroll
    for (int wt = 0; wt < 3; ++wt) if (wt < nwt)
      #pragma unroll
      for (int kh = 0; kh < 2; ++kh) {
        const int w  = w0 + wt*16 + p;
        const int j0 = kh*32 + g*8;
        FragU f; f.q = *(const uint4*)&Rs[w*RST + j0];
        ap[wt][kh] = f.v;
      }
    bf16x8 bvv[4][2];
    #pragma unroll
    for (int ot = 0; ot < 4; ++ot)
      #pragma unroll
      for (int kh = 0; kh < 2; ++kh) {
        const int o  = ot*16 + p;
        const int vv = v0 + kh*32 + g*8;
        FragU f; f.q = *(const uint4*)&VCs[o*VST + vv];
        bvv[ot][kh] = f.v;
      }
    #pragma unroll
    for (int wt = 0; wt < 3; ++wt) if (wt < nwt)
      #pragma unroll
      for (int ot = 0; ot < 4; ++ot)
        #pragma unroll
        for (int kh = 0; kh < 2; ++kh)
          oacc[wt][ot] = __builtin_amdgcn_mfma_f32_16x16x32_bf16(ap[wt][kh], bvv[ot][kh], oacc[wt][ot], 0, 0, 0);
  }

  // ---------- epilogue: normalize, stage O to LDS, coalesced residual+store ----------
  #pragma unroll
  for (int wt = 0; wt < 3; ++wt) if (wt < nwt)
    #pragma unroll
    for (int ot = 0; ot < 4; ++ot)
      #pragma unroll
      for (int r = 0; r < 4; ++r) {
        const int w = w0 + wt*16 + g*4 + r;
        const int o = ot*16 + p;
        Rs[w*RST + o] = f2bf(oacc[wt][ot][r] / lst[wt][r]);
      }
  __syncthreads();
  for (int idx = t; idx < 640; idx += 512) {
    const int w   = (idx < 320) ? idx : idx - 320;
    const int chf = (idx < 320) ? 0 : 1;
    const int cb  = chf * 32;
    #pragma unroll 8
    for (int c = 0; c < 32; ++c) {
      const int cc = cb + c;
      const int gi = base + cc*HWs + w;
      op[gi] = xq[gi] + scl[cc] * bf2f(Rs[w*RST + cc]);
    }
  }
}

extern "C" void kernel_launch(void* const* d_in, const int* in_sizes, int n_in,
                              void* d_out, int out_size, void* d_ws, size_t ws_size,
                              hipStream_t stream) {
  (void)in_sizes; (void)n_in; (void)d_ws; (void)ws_size; (void)out_size;
  sfam_kernel<<<dim3(1440), dim3(512), 0, stream>>>(
      (const float*)d_in[0],  (const float*)d_in[1],
      (const float*)d_in[2],  (const float*)d_in[3],
      (const float*)d_in[4],  (const float*)d_in[5],
      (const float*)d_in[6],  (const float*)d_in[7],
      (const float*)d_in[8],  (const float*)d_in[9],
      (const float*)d_in[10], (const float*)d_in[11],
      (const float*)d_in[12], (const float*)d_in[13],
      (const float*)d_in[14], (const float*)d_in[15],
      (float*)d_out);
}

// Round 3
// 432.919 us; speedup vs baseline: 1.1422x; 1.1422x over previous
//
#include <hip/hip_runtime.h>

// Fused SFAM, merged-direction kernel: one WG per (b,h) row-pair computes BOTH
// out_l and out_r. Exact two-pass softmax over the shared 320x320 score matrix
// (row stats for r->l, col stats for l->r). Key-side Q projection eliminated:
// S = (Q_l W~_r) x^_r^T + (Q_l b~_r) 1^T, so K = raw-LN x^_r.
// 512 threads = 8 waves; LDS ~158 KB -> 1 WG/CU.

#define HWs  57600      // H*W
#define CHWs 3686400    // C*H*W
#define TOTs 14745600   // B*C*H*W
#define RST  72         // pixel-major row stride (ushort): 64 + 8 pad
#define VST  328        // channel-major row stride (ushort): 320 + 8 pad
#define PTS  40         // Pt row stride (ushort): 32 + 8 pad

typedef short bf16x8 __attribute__((ext_vector_type(8)));
typedef float f32x4  __attribute__((ext_vector_type(4)));
union FragU { uint4 q; unsigned short u[8]; bf16x8 v; };

__device__ __forceinline__ unsigned short f2bf(float f) {
  unsigned u = __float_as_uint(f);
  u += 0x7fffu + ((u >> 16) & 1u);     // RNE
  return (unsigned short)(u >> 16);
}
__device__ __forceinline__ float bf2f(unsigned short s) {
  return __uint_as_float(((unsigned)s) << 16);
}

__global__ __launch_bounds__(512, 2) void sfam_kernel(
    const float* __restrict__ x_l, const float* __restrict__ x_r,
    const float* __restrict__ ln_l_w, const float* __restrict__ ln_l_b,
    const float* __restrict__ ln_r_w, const float* __restrict__ ln_r_b,
    const float* __restrict__ wq_l, const float* __restrict__ bq_l,
    const float* __restrict__ wq_r, const float* __restrict__ bq_r,
    const float* __restrict__ wv_l, const float* __restrict__ bv_l,
    const float* __restrict__ wv_r, const float* __restrict__ bv_r,
    const float* __restrict__ beta, const float* __restrict__ gamma,
    float* __restrict__ out)
{
  // LDS: 46080 + 46080 + 41984 + 10240 + 10240 + 2560 + 2560 + 1280 + 512 = 161536 B
  __shared__ __align__(16) unsigned short Rs[320*RST]; // x_l raw -> Q_l -> Q_l'' -> O_r
  __shared__ __align__(16) unsigned short Ks[320*RST]; // x_r raw -> x^_r -> O_l
  __shared__ __align__(16) unsigned short Vb[64*VST];  // V_l then V_r (channel-major)
  __shared__ __align__(16) unsigned short Pt[8*16*PTS];// per-wave P->A round-trip
  __shared__ float SR[8*320];   // staging partials, then colmax partials, then colmax in SR[0..320)
  __shared__ float MU[640], RSd[640];  // LN stats, [0..320)=l, [320..640)=r
  __shared__ float c_arr[320];  // c_wl = 0.125 * Q_l . b~_r
  __shared__ float BB[128];     // [0..64)=b~_l, [64..128)=b~_r

  const int bh = blockIdx.x;
  const int b = bh / 180, h = bh - b*180;
  const int base = b*CHWs + h*320;

  const int t = threadIdx.x;
  const int wave = t >> 6, lane = t & 63;
  const int p = lane & 15, g = lane >> 4;
  const int nwt = (wave < 4) ? 3 : 2;
  const int w0 = (wave < 4) ? wave*48 : 192 + (wave-4)*32;

  // ---------- A: dual concurrent staging + stats partials ----------
  for (int idx = t; idx < 1280; idx += 512) {
    int r2 = idx; const int side = (r2 >= 640); r2 -= side*640;
    const int half = (r2 >= 320); const int w = r2 - half*320;
    const int cb = half*32;
    const float* xp = side ? x_r : x_l;
    unsigned short* dst = side ? Ks : Rs;
    float s = 0.f, q = 0.f;
    #pragma unroll 8
    for (int c = 0; c < 32; ++c) {
      float v = xp[base + (cb+c)*HWs + w];
      s += v; q += v*v;
      dst[w*RST + cb + c] = f2bf(v);
    }
    SR[(side*2+half)*320 + w] = s;
    SR[(4+side*2+half)*320 + w] = q;
  }
  if (t < 128) {   // effective Q biases: b~ = bq + (W .* lnw) @ lnb
    const int o = t & 63;
    const float* wqp = (t < 64) ? wq_l : wq_r;
    const float* lwp = (t < 64) ? ln_l_w : ln_r_w;
    const float* lbp = (t < 64) ? ln_l_b : ln_r_b;
    const float* bqp = (t < 64) ? bq_l : bq_r;
    float s = bqp[o];
    for (int c = 0; c < 64; ++c) s += wqp[o*64+c]*lwp[c]*lbp[c];
    BB[t] = s;
  }
  __syncthreads();
  // 640 stats entries with 512 threads: MUST stride (round-2 bug: `if (t<640)`
  // left MU/RSd[512..639] uninitialized -> NaN).
  for (int i = t; i < 640; i += 512) {
    const int side = (i >= 320); const int w = i - side*320;
    float m = (SR[(side*2)*320+w] + SR[(side*2+1)*320+w]) * (1.f/64.f);
    float q = (SR[(4+side*2)*320+w] + SR[(4+side*2+1)*320+w]) * (1.f/64.f) - m*m;
    MU[i] = m;
    RSd[i] = rsqrtf(q + 1e-6f);
  }
  __syncthreads();

  // ---------- V projection (A = Wv, B = raw x rows; all row-local) ----------
  auto projV = [&](const float* wvp, const float* bvp, const unsigned short* src,
                   const float* mup, const float* rsp, bool inv) {
    bf16x8 bx[3][2];
    #pragma unroll
    for (int nt = 0; nt < 3; ++nt) if (nt < nwt) {
      const int w = w0 + nt*16 + p;
      const float mu = mup[w];
      const float sd = inv ? (1.0f / rsp[w]) : 0.f;
      #pragma unroll
      for (int kf = 0; kf < 2; ++kf) {
        FragU f; f.q = *(const uint4*)&src[w*RST + kf*32 + g*8];
        if (inv) {           // recover raw x from normalized: x = x^*sd + mu
          FragU rr;
          #pragma unroll
          for (int j = 0; j < 8; ++j) rr.u[j] = f2bf(bf2f(f.u[j])*sd + mu);
          bx[nt][kf] = rr.v;
        } else bx[nt][kf] = f.v;
      }
    }
    bf16x8 av[4][2];
    #pragma unroll
    for (int mt = 0; mt < 4; ++mt)
      #pragma unroll
      for (int kf = 0; kf < 2; ++kf) {
        FragU rr;
        #pragma unroll
        for (int j = 0; j < 8; ++j) rr.u[j] = f2bf(wvp[(mt*16+p)*64 + kf*32 + g*8 + j]);
        av[mt][kf] = rr.v;
      }
    f32x4 acc[4][3];
    #pragma unroll
    for (int mt = 0; mt < 4; ++mt)
      #pragma unroll
      for (int nt = 0; nt < 3; ++nt) acc[mt][nt] = (f32x4){0.f,0.f,0.f,0.f};
    #pragma unroll
    for (int mt = 0; mt < 4; ++mt)
      #pragma unroll
      for (int nt = 0; nt < 3; ++nt) if (nt < nwt)
        #pragma unroll
        for (int kf = 0; kf < 2; ++kf)
          acc[mt][nt] = __builtin_amdgcn_mfma_f32_16x16x32_bf16(av[mt][kf], bx[nt][kf], acc[mt][nt], 0,0,0);
    #pragma unroll
    for (int mt = 0; mt < 4; ++mt)
      #pragma unroll
      for (int nt = 0; nt < 3; ++nt) if (nt < nwt)
        #pragma unroll
        for (int r = 0; r < 4; ++r) {
          const int o = mt*16 + g*4 + r;
          Vb[o*VST + w0 + nt*16 + p] = f2bf(acc[mt][nt][r] + bvp[o]);
        }
  };

  projV(wv_l, bv_l, Rs, MU, RSd, false);   // Vb = V_l (from raw x_l)

  // ---------- Q_l = LN(x_l) W~_l^T + b~_l  (write in place to Rs) ----------
  float cR[3][4];
  {
    bf16x8 qa[3][2];
    #pragma unroll
    for (int wt = 0; wt < 3; ++wt) if (wt < nwt) {
      const int w = w0 + wt*16 + p;
      const float mu = MU[w], rs = RSd[w];
      #pragma unroll
      for (int kf = 0; kf < 2; ++kf) {
        FragU f; f.q = *(const uint4*)&Rs[w*RST + kf*32 + g*8];
        FragU rr;
        #pragma unroll
        for (int j = 0; j < 8; ++j) rr.u[j] = f2bf((bf2f(f.u[j]) - mu) * rs);
        qa[wt][kf] = rr.v;
      }
    }
    bf16x8 bw[4][2];
    #pragma unroll
    for (int ot = 0; ot < 4; ++ot)
      #pragma unroll
      for (int kf = 0; kf < 2; ++kf) {
        FragU rr;
        #pragma unroll
        for (int j = 0; j < 8; ++j) {
          const int c = kf*32 + g*8 + j;
          rr.u[j] = f2bf(wq_l[(ot*16+p)*64 + c] * ln_l_w[c]);
        }
        bw[ot][kf] = rr.v;
      }
    f32x4 qacc[3][4];
    #pragma unroll
    for (int wt = 0; wt < 3; ++wt)
      #pragma unroll
      for (int ot = 0; ot < 4; ++ot) qacc[wt][ot] = (f32x4){0.f,0.f,0.f,0.f};
    #pragma unroll
    for (int wt = 0; wt < 3; ++wt) if (wt < nwt)
      #pragma unroll
      for (int ot = 0; ot < 4; ++ot)
        #pragma unroll
        for (int kf = 0; kf < 2; ++kf)
          qacc[wt][ot] = __builtin_amdgcn_mfma_f32_16x16x32_bf16(qa[wt][kf], bw[ot][kf], qacc[wt][ot], 0,0,0);
    // += b~_l, write Q_l, accumulate c = Q_l . b~_r
    #pragma unroll
    for (int wt = 0; wt < 3; ++wt) {
      #pragma unroll
      for (int r = 0; r < 4; ++r) cR[wt][r] = 0.f;
      if (wt < nwt) {
        #pragma unroll
        for (int ot = 0; ot < 4; ++ot) {
          const float bl = BB[ot*16+p], br = BB[64 + ot*16+p];
          #pragma unroll
          for (int r = 0; r < 4; ++r) {
            const float qv = qacc[wt][ot][r] + bl;
            Rs[(w0 + wt*16 + g*4 + r)*RST + ot*16 + p] = f2bf(qv);
            cR[wt][r] += qv * br;
          }
        }
        #pragma unroll
        for (int r = 0; r < 4; ++r) {
          float cv = cR[wt][r];
          cv += __shfl_xor(cv, 1); cv += __shfl_xor(cv, 2);
          cv += __shfl_xor(cv, 4); cv += __shfl_xor(cv, 8);
          cv *= 0.125f;
          cR[wt][r] = cv;
          if (p == 0) c_arr[w0 + wt*16 + g*4 + r] = cv;
        }
      }
    }
  }

  // ---------- Q_l'' = 0.125 * Q_l W~_r  (in place to Rs) ----------
  {
    bf16x8 qla[3][2];
    #pragma unroll
    for (int wt = 0; wt < 3; ++wt) if (wt < nwt)
      #pragma unroll
      for (int kf = 0; kf < 2; ++kf) {
        FragU f; f.q = *(const uint4*)&Rs[(w0 + wt*16 + p)*RST + kf*32 + g*8];
        qla[wt][kf] = f.v;
      }
    bf16x8 bwt[4][2];
    #pragma unroll
    for (int ct = 0; ct < 4; ++ct) {
      const float lw = ln_r_w[ct*16 + p];
      #pragma unroll
      for (int kf = 0; kf < 2; ++kf) {
        FragU rr;
        #pragma unroll
        for (int j = 0; j < 8; ++j)
          rr.u[j] = f2bf(wq_r[(kf*32 + g*8 + j)*64 + ct*16 + p] * lw);
        bwt[ct][kf] = rr.v;
      }
    }
    f32x4 q2[3][4];
    #pragma unroll
    for (int wt = 0; wt < 3; ++wt)
      #pragma unroll
      for (int ct = 0; ct < 4; ++ct) q2[wt][ct] = (f32x4){0.f,0.f,0.f,0.f};
    #pragma unroll
    for (int wt = 0; wt < 3; ++wt) if (wt < nwt)
      #pragma unroll
      for (int ct = 0; ct < 4; ++ct)
        #pragma unroll
        for (int kf = 0; kf < 2; ++kf)
          q2[wt][ct] = __builtin_amdgcn_mfma_f32_16x16x32_bf16(qla[wt][kf], bwt[ct][kf], q2[wt][ct], 0,0,0);
    #pragma unroll
    for (int wt = 0; wt < 3; ++wt) if (wt < nwt)
      #pragma unroll
      for (int ct = 0; ct < 4; ++ct)
        #pragma unroll
        for (int r = 0; r < 4; ++r)
          Rs[(w0 + wt*16 + g*4 + r)*RST + ct*16 + p] = f2bf(q2[wt][ct][r] * 0.125f);
  }

  // ---------- normalize Ks in place: x^_r = (x_r - mu) * rs ----------
  #pragma unroll
  for (int wt = 0; wt < 3; ++wt) if (wt < nwt) {
    const int w = w0 + wt*16 + p;
    const float mu = MU[320+w], rs = RSd[320+w];
    #pragma unroll
    for (int kf = 0; kf < 2; ++kf) {
      FragU f; f.q = *(const uint4*)&Ks[w*RST + kf*32 + g*8];
      FragU rr;
      #pragma unroll
      for (int j = 0; j < 8; ++j) rr.u[j] = f2bf((bf2f(f.u[j]) - mu) * rs);
      *(uint4*)&Ks[w*RST + kf*32 + g*8] = rr.q;
    }
  }
  __syncthreads();   // Rs=Q_l'', Ks=x^_r, Vb=V_l, c_arr all visible

  // ---------- persistent A-frags ----------
  bf16x8 aq[3][2], ak[3][2];
  #pragma unroll
  for (int wt = 0; wt < 3; ++wt) if (wt < nwt)
    #pragma unroll
    for (int kf = 0; kf < 2; ++kf) {
      FragU f1; f1.q = *(const uint4*)&Rs[(w0 + wt*16 + p)*RST + kf*32 + g*8];
      aq[wt][kf] = f1.v;
      FragU f2; f2.q = *(const uint4*)&Ks[(w0 + wt*16 + p)*RST + kf*32 + g*8];
      ak[wt][kf] = f2.v;
    }

  // ---------- pass 1: S stats (rowmax exact per wave; colmax partials) ----------
  float rm[3][4];
  #pragma unroll
  for (int wt = 0; wt < 3; ++wt)
    #pragma unroll
    for (int r = 0; r < 4; ++r) rm[wt][r] = -3.0e38f;
  for (int ch = 0; ch < 5; ++ch) {
    const int k0 = ch*64;
    bf16x8 bq[4][2];
    #pragma unroll
    for (int vt = 0; vt < 4; ++vt)
      #pragma unroll
      for (int kf = 0; kf < 2; ++kf) {
        FragU f; f.q = *(const uint4*)&Ks[(k0 + vt*16 + p)*RST + kf*32 + g*8];
        bq[vt][kf] = f.v;
      }
    f32x4 sacc[3][4];
    #pragma unroll
    for (int wt = 0; wt < 3; ++wt)
      #pragma unroll
      for (int vt = 0; vt < 4; ++vt) sacc[wt][vt] = (f32x4){0.f,0.f,0.f,0.f};
    #pragma unroll
    for (int wt = 0; wt < 3; ++wt) if (wt < nwt)
      #pragma unroll
      for (int vt = 0; vt < 4; ++vt)
        #pragma unroll
        for (int kf = 0; kf < 2; ++kf)
          sacc[wt][vt] = __builtin_amdgcn_mfma_f32_16x16x32_bf16(aq[wt][kf], bq[vt][kf], sacc[wt][vt], 0,0,0);
    #pragma unroll
    for (int wt = 0; wt < 3; ++wt) if (wt < nwt) {
      #pragma unroll
      for (int r = 0; r < 4; ++r) {
        float m4 = fmaxf(fmaxf(sacc[wt][0][r], sacc[wt][1][r]),
                         fmaxf(sacc[wt][2][r], sacc[wt][3][r])) + cR[wt][r];
        m4 = fmaxf(m4, __shfl_xor(m4, 1)); m4 = fmaxf(m4, __shfl_xor(m4, 2));
        m4 = fmaxf(m4, __shfl_xor(m4, 4)); m4 = fmaxf(m4, __shfl_xor(m4, 8));
        rm[wt][r] = fmaxf(rm[wt][r], m4);
      }
    }
    #pragma unroll
    for (int vt = 0; vt < 4; ++vt) {
      float cp = -3.0e38f;
      #pragma unroll
      for (int wt = 0; wt < 3; ++wt) if (wt < nwt)
        #pragma unroll
        for (int r = 0; r < 4; ++r) cp = fmaxf(cp, sacc[wt][vt][r] + cR[wt][r]);
      cp = fmaxf(cp, __shfl_xor(cp, 16));
      cp = fmaxf(cp, __shfl_xor(cp, 32));
      if (g == 0) SR[wave*320 + k0 + vt*16 + p] = cp;
    }
  }
  __syncthreads();
  if (t < 320) {   // reduce colmax partials -> SR[0..320)
    float m = SR[t];
    #pragma unroll
    for (int j = 1; j < 8; ++j) m = fmaxf(m, SR[j*320 + t]);
    SR[t] = m;
  }
  __syncthreads();

  // ---------- shared attention pass (exp + row-sum + PV) ----------
  float ls[3][4];
  f32x4 oacc[3][4];
  auto attn_pass = [&](bf16x8 (&A)[3][2], const unsigned short* Bsrc,
                       float (&mx)[3][4], bool colc) {
    for (int ch = 0; ch < 5; ++ch) {
      const int k0 = ch*64;
      bf16x8 bq[4][2];
      #pragma unroll
      for (int vt = 0; vt < 4; ++vt)
        #pragma unroll
        for (int kf = 0; kf < 2; ++kf) {
          FragU f; f.q = *(const uint4*)&Bsrc[(k0 + vt*16 + p)*RST + kf*32 + g*8];
          bq[vt][kf] = f.v;
        }
      float cc4[4];
      #pragma unroll
      for (int vt = 0; vt < 4; ++vt) cc4[vt] = colc ? c_arr[k0 + vt*16 + p] : 0.f;
      f32x4 sacc[3][4];
      #pragma unroll
      for (int wt = 0; wt < 3; ++wt)
        #pragma unroll
        for (int vt = 0; vt < 4; ++vt) sacc[wt][vt] = (f32x4){0.f,0.f,0.f,0.f};
      #pragma unroll
      for (int wt = 0; wt < 3; ++wt) if (wt < nwt)
        #pragma unroll
        for (int vt = 0; vt < 4; ++vt)
          #pragma unroll
          for (int kf = 0; kf < 2; ++kf)
            sacc[wt][vt] = __builtin_amdgcn_mfma_f32_16x16x32_bf16(A[wt][kf], bq[vt][kf], sacc[wt][vt], 0,0,0);
      #pragma unroll
      for (int wt = 0; wt < 3; ++wt) if (wt < nwt) {
        #pragma unroll
        for (int r = 0; r < 4; ++r) {
          const float rc = colc ? 0.f : cR[wt][r];
          float rsum = 0.f;
          #pragma unroll
          for (int vt = 0; vt < 4; ++vt) {
            const float e = __expf(sacc[wt][vt][r] + rc + cc4[vt] - mx[wt][r]);
            sacc[wt][vt][r] = e; rsum += e;
          }
          rsum += __shfl_xor(rsum, 1); rsum += __shfl_xor(rsum, 2);
          rsum += __shfl_xor(rsum, 4); rsum += __shfl_xor(rsum, 8);
          ls[wt][r] += rsum;
        }
      }
      bf16x8 bvv[2][4];
      #pragma unroll
      for (int kf = 0; kf < 2; ++kf)
        #pragma unroll
        for (int ot = 0; ot < 4; ++ot) {
          FragU f; f.q = *(const uint4*)&Vb[(ot*16+p)*VST + k0 + kf*32 + g*8];
          bvv[kf][ot] = f.v;
        }
      unsigned short* ptw = &Pt[wave*16*PTS];
      #pragma unroll
      for (int wt = 0; wt < 3; ++wt) if (wt < nwt) {
        #pragma unroll
        for (int kf = 0; kf < 2; ++kf) {
          #pragma unroll
          for (int vh = 0; vh < 2; ++vh) {
            const int vt2 = kf*2 + vh;
            #pragma unroll
            for (int r = 0; r < 4; ++r)
              ptw[(g*4 + r)*PTS + vh*16 + p] = f2bf(sacc[wt][vt2][r]);
          }
          FragU fa; fa.q = *(const uint4*)&ptw[p*PTS + g*8];
          #pragma unroll
          for (int ot = 0; ot < 4; ++ot)
            oacc[wt][ot] = __builtin_amdgcn_mfma_f32_16x16x32_bf16(fa.v, bvv[kf][ot], oacc[wt][ot], 0,0,0);
        }
      }
    }
  };

  // ---------- pass 2b: dir1 (l->r). rows = wr, A = x^_r, B = Q_l'', V = V_l ----------
  float cmR[3][4];
  #pragma unroll
  for (int wt = 0; wt < 3; ++wt)
    #pragma unroll
    for (int r = 0; r < 4; ++r) {
      cmR[wt][r] = (wt < nwt) ? SR[w0 + wt*16 + g*4 + r] : 0.f;
      ls[wt][r] = 0.f;
    }
  #pragma unroll
  for (int wt = 0; wt < 3; ++wt)
    #pragma unroll
    for (int ot = 0; ot < 4; ++ot) oacc[wt][ot] = (f32x4){0.f,0.f,0.f,0.f};
  attn_pass(ak, Rs, cmR, true);
  __syncthreads();   // everyone done reading Rs (Q_l'') and Vb (V_l)

  // stash O_r -> Rs (normalized by colsum)
  #pragma unroll
  for (int wt = 0; wt < 3; ++wt) if (wt < nwt)
    #pragma unroll
    for (int r = 0; r < 4; ++r) {
      const float inv = 1.0f / ls[wt][r];
      #pragma unroll
      for (int ot = 0; ot < 4; ++ot)
        Rs[(w0 + wt*16 + g*4 + r)*RST + ot*16 + p] = f2bf(oacc[wt][ot][r] * inv);
    }

  // recompute V_r from normalized Ks (inverse LN), overwrite Vb
  projV(wv_r, bv_r, Ks, MU+320, RSd+320, true);
  __syncthreads();

  // ---------- pass 2a: dir0 (r->l). rows = wl, A = Q_l'', B = x^_r, V = V_r ----------
  #pragma unroll
  for (int wt = 0; wt < 3; ++wt)
    #pragma unroll
    for (int r = 0; r < 4; ++r) ls[wt][r] = 0.f;
  #pragma unroll
  for (int wt = 0; wt < 3; ++wt)
    #pragma unroll
    for (int ot = 0; ot < 4; ++ot) oacc[wt][ot] = (f32x4){0.f,0.f,0.f,0.f};
  attn_pass(aq, Ks, rm, false);
  __syncthreads();   // everyone done reading Ks (x^_r) and Vb (V_r)

  // stash O_l -> Ks (normalized by rowsum)
  #pragma unroll
  for (int wt = 0; wt < 3; ++wt) if (wt < nwt)
    #pragma unroll
    for (int r = 0; r < 4; ++r) {
      const float inv = 1.0f / ls[wt][r];
      #pragma unroll
      for (int ot = 0; ot < 4; ++ot)
        Ks[(w0 + wt*16 + g*4 + r)*RST + ot*16 + p] = f2bf(oacc[wt][ot][r] * inv);
    }
  __syncthreads();

  // ---------- epilogue: residual add + store, both sides ----------
  for (int idx = t; idx < 1280; idx += 512) {
    int r2 = idx; const int side = (r2 >= 640); r2 -= side*640;
    const int half = (r2 >= 320); const int w = r2 - half*320;
    const int cb = half*32;
    const float* xs = side ? x_r : x_l;
    const unsigned short* Osrc = side ? Rs : Ks;   // O_r in Rs, O_l in Ks
    const float* sc = side ? gamma : beta;
    float* op = out + (side ? TOTs : 0);
    #pragma unroll 8
    for (int c = 0; c < 32; ++c) {
      const int cc = cb + c;
      const int gi = base + cc*HWs + w;
      op[gi] = xs[gi] + sc[cc] * bf2f(Osrc[w*RST + cc]);
    }
  }
}

extern "C" void kernel_launch(void* const* d_in, const int* in_sizes, int n_in,
                              void* d_out, int out_size, void* d_ws, size_t ws_size,
                              hipStream_t stream) {
  (void)in_sizes; (void)n_in; (void)d_ws; (void)ws_size; (void)out_size;
  sfam_kernel<<<dim3(720), dim3(512), 0, stream>>>(
      (const float*)d_in[0],  (const float*)d_in[1],
      (const float*)d_in[2],  (const float*)d_in[3],
      (const float*)d_in[4],  (const float*)d_in[5],
      (const float*)d_in[6],  (const float*)d_in[7],
      (const float*)d_in[8],  (const float*)d_in[9],
      (const float*)d_in[10], (const float*)d_in[11],
      (const float*)d_in[12], (const float*)d_in[13],
      (const float*)d_in[14], (const float*)d_in[15],
      (float*)d_out);
}